// Round 4
// baseline (210.676 us; speedup 1.0000x reference)
//
#include <hip/hip_runtime.h>
#include <math.h>

// B=4, H=W=64, C=128, NH=4, HD=32, K=7, TOK=16384
#define TOK 16384

typedef __attribute__((ext_vector_type(8))) __bf16 bf16x8;
typedef __attribute__((ext_vector_type(4))) float f32x4;

__device__ inline unsigned short f2bf(float f) {
    union { float f; unsigned int u; } v; v.f = f;
    unsigned int r = v.u + 0x7fffu + ((v.u >> 16) & 1u);
    return (unsigned short)(r >> 16);
}

// ---------------- LayerNorm body: one wave per token, 2 ch/lane, bf16 out ----
__device__ inline void ln_body(const float* __restrict__ x, const float* __restrict__ g,
                               const float* __restrict__ b, unsigned short* __restrict__ y,
                               int tok, int lane)
{
    float2 v = ((const float2*)(x + (size_t)tok * 128))[lane];
    float s = v.x + v.y;
#pragma unroll
    for (int m = 32; m >= 1; m >>= 1) s += __shfl_xor(s, m);
    float mean = s * (1.0f / 128.0f);
    float dx = v.x - mean, dy = v.y - mean;
    float vs = dx * dx + dy * dy;
#pragma unroll
    for (int m = 32; m >= 1; m >>= 1) vs += __shfl_xor(vs, m);
    float rs = rsqrtf(vs * (1.0f / 128.0f) + 1e-5f);
    float2 gg = ((const float2*)g)[lane];
    float2 bb = ((const float2*)b)[lane];
    float ox = dx * rs * gg.x + bb.x;
    float oy = dy * rs * gg.y + bb.y;
    unsigned int pk = (unsigned int)f2bf(ox) | ((unsigned int)f2bf(oy) << 16);
    ((unsigned int*)(y + (size_t)tok * 128))[lane] = pk;
}

// ---------------- prep: LN1 + LN2 + weight transpose/convert to bf16 --------
__global__ __launch_bounds__(256) void prep_kernel(
    const float* __restrict__ query, const float* __restrict__ key_value,
    const float* __restrict__ g1, const float* __restrict__ b1,
    const float* __restrict__ g2, const float* __restrict__ b2,
    const float* __restrict__ Wq, const float* __restrict__ Wkv,
    const float* __restrict__ Wp, const float* __restrict__ W1, const float* __restrict__ W2,
    unsigned short* __restrict__ qnh, unsigned short* __restrict__ kvnh,
    unsigned short* __restrict__ Wt)
{
    int blk = blockIdx.x, tid = threadIdx.x;
    if (blk < 8192) {
        int lane = tid & 63;
        if (blk < 4096) ln_body(query,     g1, b1, qnh,  blk * 4 + (tid >> 6), lane);
        else            ln_body(key_value, g2, b2, kvnh, (blk - 4096) * 4 + (tid >> 6), lane);
        return;
    }
    int gid = (blk - 8192) * 256 + tid;   // [0, 196608)
    const float* src; int Kd, Nd, li;
    if      (gid < 16384)  { src = Wq;  Kd = 128; Nd = 128; li = gid; }
    else if (gid < 49152)  { src = Wkv; Kd = 128; Nd = 256; li = gid - 16384; }
    else if (gid < 65536)  { src = Wp;  Kd = 128; Nd = 128; li = gid - 49152; }
    else if (gid < 131072) { src = W1;  Kd = 128; Nd = 512; li = gid - 65536; }
    else                   { src = W2;  Kd = 512; Nd = 128; li = gid - 131072; }
    int n = li / Kd, k = li % Kd;
    Wt[gid] = f2bf(src[(size_t)k * Nd + n]);
}

// ---------------- standalone LN (LN3), bf16 out -----------------------------
__global__ __launch_bounds__(256) void ln3_kernel(const float* __restrict__ x,
    const float* __restrict__ g, const float* __restrict__ b, unsigned short* __restrict__ y)
{
    ln_body(x, g, b, y, blockIdx.x * 4 + (threadIdx.x >> 6), threadIdx.x & 63);
}

// ---------------- bf16 MFMA GEMM: wave tile 32x64, no LDS, direct global ----
// MODE 0: outH = bf16(v*scale)
// MODE 1: outF = v + res
// MODE 2: outH = bf16(gelu_exact(v))
// MODE 3: KV fused: cols<128 -> outH bf16 [tok][128]; cols>=128 -> vtg[bh*32+d][pos]
template<int MODE>
__global__ __launch_bounds__(256) void gemm_mfma(
    const unsigned short* __restrict__ A, const unsigned short* __restrict__ Wt,
    const float* __restrict__ bias, const float* __restrict__ res,
    float* __restrict__ outF, unsigned short* __restrict__ outH,
    unsigned short* __restrict__ vtg,
    int M, int N, int K, float scale)
{
    const int wave = threadIdx.x >> 6, lane = threadIdx.x & 63;
    const int wm = wave & 1, wn = wave >> 1;
    const int m0 = blockIdx.x * 64 + wm * 32;
    const int n0 = blockIdx.y * 128 + wn * 64;
    const int lr = lane & 15;
    const int lg = lane >> 4;
    f32x4 acc[2][4] = {};
#pragma unroll 4
    for (int k0 = 0; k0 < K; k0 += 32) {
        bf16x8 a[2], b[4];
#pragma unroll
        for (int mf = 0; mf < 2; ++mf)
            a[mf] = *(const bf16x8*)(A + (size_t)(m0 + mf * 16 + lr) * K + k0 + lg * 8);
#pragma unroll
        for (int nf = 0; nf < 4; ++nf)
            b[nf] = *(const bf16x8*)(Wt + (size_t)(n0 + nf * 16 + lr) * K + k0 + lg * 8);
#pragma unroll
        for (int mf = 0; mf < 2; ++mf)
#pragma unroll
            for (int nf = 0; nf < 4; ++nf)
                acc[mf][nf] = __builtin_amdgcn_mfma_f32_16x16x32_bf16(a[mf], b[nf], acc[mf][nf], 0, 0, 0);
    }
    // C/D layout: col = lane&15, row = (lane>>4)*4 + reg
#pragma unroll
    for (int nf = 0; nf < 4; ++nf) {
        int gc = n0 + nf * 16 + lr;
        float bs = bias[gc];
        if (MODE == 3 && gc >= 128) {
            // V: transposed write vtg[((b*4+h)*32+d)][pos], 4 tokens packed
            int d = gc - 128;
            int hh = d >> 5, dd = d & 31;
#pragma unroll
            for (int mf = 0; mf < 2; ++mf) {
                int gr0 = m0 + mf * 16 + lg * 4;
                int bidx = gr0 >> 12, pos = gr0 & 4095;
                ushort4 pk;
                pk.x = f2bf(acc[mf][nf][0] + bs);
                pk.y = f2bf(acc[mf][nf][1] + bs);
                pk.z = f2bf(acc[mf][nf][2] + bs);
                pk.w = f2bf(acc[mf][nf][3] + bs);
                *(ushort4*)(vtg + ((size_t)((bidx * 4 + hh) * 32 + dd)) * 4096 + pos) = pk;
            }
            continue;
        }
#pragma unroll
        for (int mf = 0; mf < 2; ++mf) {
            int gr0 = m0 + mf * 16 + lg * 4;
#pragma unroll
            for (int r = 0; r < 4; ++r) {
                float v = acc[mf][nf][r] + bs;
                if (MODE == 0) outH[(size_t)(gr0 + r) * N + gc] = f2bf(v * scale);
                if (MODE == 1) { size_t idx = (size_t)(gr0 + r) * N + gc; outF[idx] = v + res[idx]; }
                if (MODE == 2) {
                    float gl = 0.5f * v * (1.0f + erff(v * 0.70710678118654752f));
                    outH[(size_t)(gr0 + r) * N + gc] = f2bf(gl);
                }
                if (MODE == 3) outH[(size_t)(gr0 + r) * 128 + gc] = f2bf(v);
            }
        }
    }
}

// ---------------- Neighborhood attention via MFMA ---------------------------
// Block = (b, head, 8x8 query tile); wave w handles 16 queries (image rows 2w,2w+1).
// Keys: 14x16 padded halo (hr = kb, hc = col). No __syncthreads anywhere.
__global__ __launch_bounds__(256) void nat_attn(
    const unsigned short* __restrict__ qbh,   // [TOK][128] bf16 (pre-scaled)
    const unsigned short* __restrict__ kbh,   // [TOK][128] bf16
    const unsigned short* __restrict__ vtg,   // [(b*4+h)*32+d][4096] bf16
    const float* __restrict__ rpb,            // [4][13][13]
    unsigned short* __restrict__ out)         // [TOK][128] bf16
{
    __shared__ __align__(16) unsigned short Pbuf[4][16][232];
    const int tid = threadIdx.x;
    const int wave = tid >> 6, lane = tid & 63;
    const int c = lane & 15, lg = lane >> 4;
    const int bid = blockIdx.x;
    const int tile = bid & 63, h = (bid >> 6) & 3, b = bid >> 8;
    const int ti0 = (tile >> 3) * 8, tj0 = (tile & 7) * 8;
    const int hr0 = min(max(ti0 - 3, 0), 50);
    const int hc0 = min(max(tj0 - 3, 0), 50);
    const int bb = b << 12;

    // ---- Q A-frag (m = c): query geometry for lane's fragment row
    const int gi_m = ti0 + wave * 2 + (c >> 3);
    const int gj_m = tj0 + (c & 7);
    const int tq = bb + gi_m * 64 + gj_m;
    bf16x8 qf = *(const bf16x8*)(qbh + (size_t)tq * 128 + h * 32 + lg * 8);

    // ---- QK^T: 14 mfmas; key p = kb*16 + c -> token bb + (hr0+kb)*64 + hc0 + c
    f32x4 S[14] = {};
    const int tk0 = bb + hr0 * 64 + hc0 + c;
#pragma unroll
    for (int kb = 0; kb < 14; ++kb) {
        bf16x8 kf = *(const bf16x8*)(kbh + (size_t)(tk0 + kb * 64) * 128 + h * 32 + lg * 8);
        S[kb] = __builtin_amdgcn_mfma_f32_16x16x32_bf16(qf, kf, S[kb], 0, 0, 0);
    }

    // ---- bias + mask + softmax in C layout (row = lg*4+i, col = c)
#pragma unroll
    for (int i = 0; i < 4; ++i) {
        int m = lg * 4 + i;
        int gi = ti0 + wave * 2 + (m >> 3);
        int gj = tj0 + (m & 7);
        int si = min(max(gi - 3, 0), 57), sj = min(max(gj - 3, 0), 57);
        bool cv = (unsigned)(hc0 + c - sj) < 7u;
        int rjc = min(max(hc0 + c - gj + 6, 0), 12);
        int rbase = h * 169 + rjc;
        float mxi = -INFINITY;
#pragma unroll
        for (int kb = 0; kb < 14; ++kb) {
            bool rv = (unsigned)(hr0 + kb - si) < 7u;
            int ric = min(max(hr0 + kb - gi + 6, 0), 12);
            float bias = rpb[rbase + ric * 13];
            float s = (rv && cv) ? S[kb][i] + bias : -1e30f;
            S[kb][i] = s;
            mxi = fmaxf(mxi, s);
        }
        mxi = fmaxf(mxi, __shfl_xor(mxi, 1));
        mxi = fmaxf(mxi, __shfl_xor(mxi, 2));
        mxi = fmaxf(mxi, __shfl_xor(mxi, 4));
        mxi = fmaxf(mxi, __shfl_xor(mxi, 8));
        float smi = 0.0f;
#pragma unroll
        for (int kb = 0; kb < 14; ++kb) {
            float e = expf(S[kb][i] - mxi);
            S[kb][i] = e;
            smi += e;
        }
        smi += __shfl_xor(smi, 1);
        smi += __shfl_xor(smi, 2);
        smi += __shfl_xor(smi, 4);
        smi += __shfl_xor(smi, 8);
        float rinv = 1.0f / smi;
#pragma unroll
        for (int kb = 0; kb < 14; ++kb)
            Pbuf[wave][m][kb * 16 + c] = f2bf(S[kb][i] * rinv);
    }

    // ---- PV: P A-frags from wave-private LDS, V B-frags from transposed global
    f32x4 O[2] = {};
#pragma unroll
    for (int ks = 0; ks < 7; ++ks) {
        bf16x8 pf = *(const bf16x8*)&Pbuf[wave][c][ks * 32 + lg * 8];
        int p0 = ks * 32 + lg * 8;
        size_t posa = (size_t)(hr0 + (p0 >> 4)) * 64 + hc0 + (p0 & 15);
#pragma unroll
        for (int nb = 0; nb < 2; ++nb) {
            bf16x8 vf = *(const bf16x8*)(vtg + ((size_t)((b * 4 + h) * 32 + nb * 16 + c)) * 4096 + posa);
            O[nb] = __builtin_amdgcn_mfma_f32_16x16x32_bf16(pf, vf, O[nb], 0, 0, 0);
        }
    }
    // ---- write out (C layout)
#pragma unroll
    for (int i = 0; i < 4; ++i) {
        int m = lg * 4 + i;
        int gi = ti0 + wave * 2 + (m >> 3);
        int gj = tj0 + (m & 7);
        size_t t = ((size_t)(bb + gi * 64 + gj)) * 128 + h * 32;
        out[t + c]      = f2bf(O[0][i]);
        out[t + 16 + c] = f2bf(O[1][i]);
    }
}

extern "C" void kernel_launch(void* const* d_in, const int* in_sizes, int n_in,
                              void* d_out, int out_size, void* d_ws, size_t ws_size,
                              hipStream_t stream) {
    const float* query     = (const float*)d_in[0];
    const float* key_value = (const float*)d_in[1];
    const float* g1 = (const float*)d_in[2];
    const float* b1 = (const float*)d_in[3];
    const float* g2 = (const float*)d_in[4];
    const float* b2 = (const float*)d_in[5];
    const float* g3 = (const float*)d_in[6];
    const float* b3 = (const float*)d_in[7];
    const float* Wq  = (const float*)d_in[8];
    const float* bq  = (const float*)d_in[9];
    const float* Wkv = (const float*)d_in[10];
    const float* bkv = (const float*)d_in[11];
    const float* Wp  = (const float*)d_in[12];
    const float* bp  = (const float*)d_in[13];
    const float* rpb = (const float*)d_in[14];
    const float* W1  = (const float*)d_in[15];
    const float* bm1 = (const float*)d_in[16];
    const float* W2  = (const float*)d_in[17];
    const float* bm2 = (const float*)d_in[18];

    char* ws = (char*)d_ws;
    // byte layout, total ~46.5 MB (ws >= 58.7 MB). Halo reads may overrun a
    // region by <4 KB into the next one — reads only, values masked, finite.
    float*          xb   = (float*)(ws + 0);                  //  8 MB f32 [TOK][128]
    unsigned short* bufD = (unsigned short*)(ws + 8388608);   //  4 MB bf16: qnh -> attnh
    unsigned short* kvnh = (unsigned short*)(ws + 12582912);  //  4 MB bf16: kvn -> xnh
    unsigned short* qbh  = (unsigned short*)(ws + 16777216);  //  4 MB bf16 [TOK][128]
    unsigned short* kbh  = (unsigned short*)(ws + 20971520);  //  4 MB bf16 [TOK][128]
    unsigned short* vtg  = (unsigned short*)(ws + 25165824);  //  4 MB bf16 [16*32][4096]
    unsigned short* h1h  = (unsigned short*)(ws + 29360128);  // 16 MB bf16 [TOK][512]
    unsigned short* Wt   = (unsigned short*)(ws + 46137344);  // 384 KB bf16
    unsigned short* WtQ  = Wt;
    unsigned short* WtKV = Wt + 16384;
    unsigned short* WtP  = Wt + 49152;
    unsigned short* WtW1 = Wt + 65536;
    unsigned short* WtW2 = Wt + 131072;

    const float qscale = 0.17677669529663687f;  // HD^-0.5

    prep_kernel<<<8960, 256, 0, stream>>>(query, key_value, g1, b1, g2, b2,
                                          Wq, Wkv, Wp, W1, W2, bufD, kvnh, Wt);
    gemm_mfma<0><<<dim3(TOK / 64, 1), 256, 0, stream>>>(bufD, WtQ,  bq,  nullptr, nullptr, qbh, nullptr, TOK, 128, 128, qscale);
    gemm_mfma<3><<<dim3(TOK / 64, 2), 256, 0, stream>>>(kvnh, WtKV, bkv, nullptr, nullptr, kbh, vtg,     TOK, 256, 128, 1.0f);
    nat_attn<<<1024, 256, 0, stream>>>(qbh, kbh, vtg, rpb, bufD);
    gemm_mfma<1><<<dim3(TOK / 64, 1), 256, 0, stream>>>(bufD, WtP,  bp,  key_value, xb, nullptr, nullptr, TOK, 128, 128, 1.0f);
    ln3_kernel<<<4096, 256, 0, stream>>>(xb, g3, b3, kvnh);
    gemm_mfma<2><<<dim3(TOK / 64, 4), 256, 0, stream>>>(kvnh, WtW1, bm1, nullptr, nullptr, h1h, nullptr, TOK, 512, 128, 1.0f);
    gemm_mfma<1><<<dim3(TOK / 64, 1), 256, 0, stream>>>(h1h,  WtW2, bm2, xb, (float*)d_out, nullptr, nullptr, TOK, 128, 512, 1.0f);
}

// Round 5
// 206.339 us; speedup vs baseline: 1.0210x; 1.0210x over previous
//
#include <hip/hip_runtime.h>
#include <math.h>

// B=4, H=W=64, C=128, NH=4, HD=32, K=7, TOK=16384
#define TOK 16384

typedef __attribute__((ext_vector_type(8))) __bf16 bf16x8;
typedef __attribute__((ext_vector_type(4))) float f32x4;

__device__ inline unsigned short f2bf(float f) {
    union { float f; unsigned int u; } v; v.f = f;
    unsigned int r = v.u + 0x7fffu + ((v.u >> 16) & 1u);
    return (unsigned short)(r >> 16);
}

// ---------------- LayerNorm body: one wave per token, 2 ch/lane, bf16 out ----
__device__ inline void ln_body(const float* __restrict__ x, const float* __restrict__ g,
                               const float* __restrict__ b, unsigned short* __restrict__ y,
                               int tok, int lane)
{
    float2 v = ((const float2*)(x + (size_t)tok * 128))[lane];
    float s = v.x + v.y;
#pragma unroll
    for (int m = 32; m >= 1; m >>= 1) s += __shfl_xor(s, m);
    float mean = s * (1.0f / 128.0f);
    float dx = v.x - mean, dy = v.y - mean;
    float vs = dx * dx + dy * dy;
#pragma unroll
    for (int m = 32; m >= 1; m >>= 1) vs += __shfl_xor(vs, m);
    float rs = rsqrtf(vs * (1.0f / 128.0f) + 1e-5f);
    float2 gg = ((const float2*)g)[lane];
    float2 bb = ((const float2*)b)[lane];
    float ox = dx * rs * gg.x + bb.x;
    float oy = dy * rs * gg.y + bb.y;
    unsigned int pk = (unsigned int)f2bf(ox) | ((unsigned int)f2bf(oy) << 16);
    ((unsigned int*)(y + (size_t)tok * 128))[lane] = pk;
}

// ---------------- prep: LN1 + LN2 + tiled weight transpose to bf16 ----------
// blocks [0,4096): LN1  [4096,8192): LN2  [8192,8384): 192 32x32 transpose tiles
__global__ __launch_bounds__(256) void prep_kernel(
    const float* __restrict__ query, const float* __restrict__ key_value,
    const float* __restrict__ g1, const float* __restrict__ b1,
    const float* __restrict__ g2, const float* __restrict__ b2,
    const float* __restrict__ Wq, const float* __restrict__ Wkv,
    const float* __restrict__ Wp, const float* __restrict__ W1, const float* __restrict__ W2,
    unsigned short* __restrict__ qnh, unsigned short* __restrict__ kvnh,
    unsigned short* __restrict__ Wt)
{
    int blk = blockIdx.x, tid = threadIdx.x;
    if (blk < 8192) {
        int lane = tid & 63;
        if (blk < 4096) ln_body(query,     g1, b1, qnh,  blk * 4 + (tid >> 6), lane);
        else            ln_body(key_value, g2, b2, kvnh, (blk - 4096) * 4 + (tid >> 6), lane);
        return;
    }
    __shared__ float tile[32][33];
    int t = blk - 8192;
    const float* src; unsigned short* dst; int Kd, Nd, li;
    if      (t < 16)  { src = Wq;  dst = Wt;          Kd = 128; Nd = 128; li = t; }
    else if (t < 48)  { src = Wkv; dst = Wt + 16384;  Kd = 128; Nd = 256; li = t - 16; }
    else if (t < 64)  { src = Wp;  dst = Wt + 49152;  Kd = 128; Nd = 128; li = t - 48; }
    else if (t < 128) { src = W1;  dst = Wt + 65536;  Kd = 128; Nd = 512; li = t - 64; }
    else              { src = W2;  dst = Wt + 131072; Kd = 512; Nd = 128; li = t - 128; }
    int ntc = Nd >> 5;
    int k0 = (li / ntc) * 32, n0 = (li % ntc) * 32;
    int r = tid >> 3, c4 = (tid & 7) * 4;
    float4 v = *(const float4*)(src + (size_t)(k0 + r) * Nd + n0 + c4);
    tile[r][c4 + 0] = v.x; tile[r][c4 + 1] = v.y;
    tile[r][c4 + 2] = v.z; tile[r][c4 + 3] = v.w;
    __syncthreads();
    ushort4 o;
    o.x = f2bf(tile[c4 + 0][r]);
    o.y = f2bf(tile[c4 + 1][r]);
    o.z = f2bf(tile[c4 + 2][r]);
    o.w = f2bf(tile[c4 + 3][r]);
    *(ushort4*)(dst + (size_t)(n0 + r) * Kd + k0 + c4) = o;
}

// ---------------- bf16 MFMA GEMM: block 64x64 (4 waves of 32x32), K unrolled -
// MODE 0: outH = bf16(v*scale)   MODE 1: outF = v + res (f32)
// MODE 2: outH = bf16(gelu(v))   MODE 3: KV fused (kbh + transposed vtg)
template<int MODE, int TK>
__global__ __launch_bounds__(256) void gemm_mfma(
    const unsigned short* __restrict__ A, const unsigned short* __restrict__ Wt,
    const float* __restrict__ bias, const float* __restrict__ res,
    float* __restrict__ outF, unsigned short* __restrict__ outH,
    unsigned short* __restrict__ vtg, int N, float scale)
{
    const int wave = threadIdx.x >> 6, lane = threadIdx.x & 63;
    const int wm = wave & 1, wn = wave >> 1;
    const int m0 = blockIdx.x * 64 + wm * 32;
    const int n0 = blockIdx.y * 64 + wn * 32;
    const int lr = lane & 15, lg = lane >> 4;
    f32x4 acc[2][2] = {};
#pragma unroll 8
    for (int k0 = 0; k0 < TK; k0 += 32) {
        bf16x8 a[2], b[2];
#pragma unroll
        for (int mf = 0; mf < 2; ++mf)
            a[mf] = *(const bf16x8*)(A + (size_t)(m0 + mf * 16 + lr) * TK + k0 + lg * 8);
#pragma unroll
        for (int nf = 0; nf < 2; ++nf)
            b[nf] = *(const bf16x8*)(Wt + (size_t)(n0 + nf * 16 + lr) * TK + k0 + lg * 8);
#pragma unroll
        for (int mf = 0; mf < 2; ++mf)
#pragma unroll
            for (int nf = 0; nf < 2; ++nf)
                acc[mf][nf] = __builtin_amdgcn_mfma_f32_16x16x32_bf16(a[mf], b[nf], acc[mf][nf], 0, 0, 0);
    }
    // C/D layout: col = lane&15, row = (lane>>4)*4 + reg
#pragma unroll
    for (int nf = 0; nf < 2; ++nf) {
        int gc = n0 + nf * 16 + lr;
        float bs = bias[gc];
        if (MODE == 3 && gc >= 128) {
            int d = gc - 128;
            int hh = d >> 5, dd = d & 31;
#pragma unroll
            for (int mf = 0; mf < 2; ++mf) {
                int gr0 = m0 + mf * 16 + lg * 4;
                int bidx = gr0 >> 12, pos = gr0 & 4095;
                ushort4 pk;
                pk.x = f2bf(acc[mf][nf][0] + bs);
                pk.y = f2bf(acc[mf][nf][1] + bs);
                pk.z = f2bf(acc[mf][nf][2] + bs);
                pk.w = f2bf(acc[mf][nf][3] + bs);
                *(ushort4*)(vtg + ((size_t)((bidx * 4 + hh) * 32 + dd)) * 4096 + pos) = pk;
            }
            continue;
        }
#pragma unroll
        for (int mf = 0; mf < 2; ++mf) {
            int gr0 = m0 + mf * 16 + lg * 4;
#pragma unroll
            for (int r = 0; r < 4; ++r) {
                float v = acc[mf][nf][r] + bs;
                if (MODE == 0) outH[(size_t)(gr0 + r) * N + gc] = f2bf(v * scale);
                if (MODE == 1) { size_t idx = (size_t)(gr0 + r) * N + gc; outF[idx] = v + res[idx]; }
                if (MODE == 2) {
                    float gl = 0.5f * v * (1.0f + erff(v * 0.70710678118654752f));
                    outH[(size_t)(gr0 + r) * N + gc] = f2bf(gl);
                }
                if (MODE == 3) outH[(size_t)(gr0 + r) * 128 + gc] = f2bf(v);
            }
        }
    }
}

// ---------------- Wp GEMM + residual + fused LN3 ----------------------------
// Block = 32 rows x full 128 cols (4 waves of 32x32). xb = x (f32), y = bf16 LN(x).
__global__ __launch_bounds__(256) void gemm_p_ln(
    const unsigned short* __restrict__ A, const unsigned short* __restrict__ Wt,
    const float* __restrict__ bias, const float* __restrict__ res,
    const float* __restrict__ g, const float* __restrict__ bln,
    float* __restrict__ xb, unsigned short* __restrict__ y)
{
    __shared__ float xs[32][132];
    const int wave = threadIdx.x >> 6, lane = threadIdx.x & 63;
    const int m0 = blockIdx.x * 32;
    const int n0 = wave * 32;
    const int lr = lane & 15, lg = lane >> 4;
    f32x4 acc[2][2] = {};
#pragma unroll
    for (int k0 = 0; k0 < 128; k0 += 32) {
        bf16x8 a[2], b[2];
#pragma unroll
        for (int mf = 0; mf < 2; ++mf)
            a[mf] = *(const bf16x8*)(A + (size_t)(m0 + mf * 16 + lr) * 128 + k0 + lg * 8);
#pragma unroll
        for (int nf = 0; nf < 2; ++nf)
            b[nf] = *(const bf16x8*)(Wt + (size_t)(n0 + nf * 16 + lr) * 128 + k0 + lg * 8);
#pragma unroll
        for (int mf = 0; mf < 2; ++mf)
#pragma unroll
            for (int nf = 0; nf < 2; ++nf)
                acc[mf][nf] = __builtin_amdgcn_mfma_f32_16x16x32_bf16(a[mf], b[nf], acc[mf][nf], 0, 0, 0);
    }
#pragma unroll
    for (int nf = 0; nf < 2; ++nf) {
        int gc = n0 + nf * 16 + lr;
        float bs = bias[gc];
#pragma unroll
        for (int mf = 0; mf < 2; ++mf) {
            int lr0 = mf * 16 + lg * 4;
#pragma unroll
            for (int r = 0; r < 4; ++r) {
                size_t idx = (size_t)(m0 + lr0 + r) * 128 + gc;
                float v = acc[mf][nf][r] + bs + res[idx];
                xb[idx] = v;
                xs[lr0 + r][gc] = v;
            }
        }
    }
    __syncthreads();
    // LN: 8 threads per row, 16 ch each
    const int r = threadIdx.x >> 3, t8 = threadIdx.x & 7;
    float vals[16];
#pragma unroll
    for (int j = 0; j < 16; ++j) vals[j] = xs[r][t8 * 16 + j];
    float s = 0.0f;
#pragma unroll
    for (int j = 0; j < 16; ++j) s += vals[j];
    s += __shfl_xor(s, 1); s += __shfl_xor(s, 2); s += __shfl_xor(s, 4);
    float mean = s * (1.0f / 128.0f);
    float vv = 0.0f;
#pragma unroll
    for (int j = 0; j < 16; ++j) { float d = vals[j] - mean; vv += d * d; }
    vv += __shfl_xor(vv, 1); vv += __shfl_xor(vv, 2); vv += __shfl_xor(vv, 4);
    float rs = rsqrtf(vv * (1.0f / 128.0f) + 1e-5f);
#pragma unroll
    for (int jj = 0; jj < 4; ++jj) {
        float4 gg = ((const float4*)g)[t8 * 4 + jj];
        float4 bb = ((const float4*)bln)[t8 * 4 + jj];
        ushort4 o;
        o.x = f2bf((vals[jj * 4 + 0] - mean) * rs * gg.x + bb.x);
        o.y = f2bf((vals[jj * 4 + 1] - mean) * rs * gg.y + bb.y);
        o.z = f2bf((vals[jj * 4 + 2] - mean) * rs * gg.z + bb.z);
        o.w = f2bf((vals[jj * 4 + 3] - mean) * rs * gg.w + bb.w);
        *(ushort4*)(y + (size_t)(m0 + r) * 128 + t8 * 16 + jj * 4) = o;
    }
}

// ---------------- Neighborhood attention via MFMA, prefetched ---------------
// Block = (b, head, 8x8 query tile); wave w: 16 queries (image rows 2w, 2w+1).
// rpb staged in LDS; K frags (14) and V frags (14) fully prefetched to regs.
__global__ __launch_bounds__(256) void nat_attn(
    const unsigned short* __restrict__ qbh,   // [TOK][128] bf16 (pre-scaled)
    const unsigned short* __restrict__ kbh,   // [TOK][128] bf16
    const unsigned short* __restrict__ vtg,   // [(b*4+h)*32+d][4096] bf16
    const float* __restrict__ rpb,            // [4][13][13]
    unsigned short* __restrict__ out)         // [TOK][128] bf16
{
    __shared__ __align__(16) unsigned short Pbuf[4][16][232];
    __shared__ float rpbs[169];
    const int tid = threadIdx.x;
    const int wave = tid >> 6, lane = tid & 63;
    const int c = lane & 15, lg = lane >> 4;
    const int bid = blockIdx.x;
    const int tile = bid & 63, h = (bid >> 6) & 3, b = bid >> 8;
    const int ti0 = (tile >> 3) * 8, tj0 = (tile & 7) * 8;
    const int hr0 = min(max(ti0 - 3, 0), 50);
    const int hc0 = min(max(tj0 - 3, 0), 50);
    const int bb = b << 12;
    if (tid < 169) rpbs[tid] = rpb[h * 169 + tid];
    __syncthreads();

    // ---- Q A-frag (m = c)
    const int gi_m = ti0 + wave * 2 + (c >> 3);
    const int gj_m = tj0 + (c & 7);
    const int tq = bb + gi_m * 64 + gj_m;
    bf16x8 qf = *(const bf16x8*)(qbh + (size_t)tq * 128 + h * 32 + lg * 8);

    // ---- all 14 K-frag loads issued up front
    bf16x8 kf[14];
    const int tk0 = bb + hr0 * 64 + hc0 + c;
#pragma unroll
    for (int kb = 0; kb < 14; ++kb)
        kf[kb] = *(const bf16x8*)(kbh + (size_t)(tk0 + kb * 64) * 128 + h * 32 + lg * 8);

    f32x4 S[14];
#pragma unroll
    for (int kb = 0; kb < 14; ++kb) {
        f32x4 z = {0.0f, 0.0f, 0.0f, 0.0f};
        S[kb] = __builtin_amdgcn_mfma_f32_16x16x32_bf16(qf, kf[kb], z, 0, 0, 0);
    }

    // ---- prefetch all V frags (latency hides under softmax)
    bf16x8 vf[7][2];
    const size_t vbase = (size_t)((b * 4 + h) * 32) * 4096;
#pragma unroll
    for (int ks = 0; ks < 7; ++ks) {
        int p0 = ks * 32 + lg * 8;
        size_t posa = (size_t)(hr0 + (p0 >> 4)) * 64 + hc0 + (p0 & 15);
#pragma unroll
        for (int nb = 0; nb < 2; ++nb)
            vf[ks][nb] = *(const bf16x8*)(vtg + vbase + (size_t)(nb * 16 + c) * 4096 + posa);
    }

    // ---- bias + mask + softmax in C layout (row = lg*4+i, col = c), rpb in LDS
#pragma unroll
    for (int i = 0; i < 4; ++i) {
        int m = lg * 4 + i;
        int gi = ti0 + wave * 2 + (m >> 3);
        int gj = tj0 + (m & 7);
        int si = min(max(gi - 3, 0), 57), sj = min(max(gj - 3, 0), 57);
        bool cv = (unsigned)(hc0 + c - sj) < 7u;
        int rjc = min(max(hc0 + c - gj + 6, 0), 12);
        float mxi = -INFINITY;
#pragma unroll
        for (int kb = 0; kb < 14; ++kb) {
            bool rv = (unsigned)(hr0 + kb - si) < 7u;
            int ric = min(max(hr0 + kb - gi + 6, 0), 12);
            float bias = rpbs[rjc + ric * 13];
            float s = (rv && cv) ? S[kb][i] + bias : -1e30f;
            S[kb][i] = s;
            mxi = fmaxf(mxi, s);
        }
        mxi = fmaxf(mxi, __shfl_xor(mxi, 1));
        mxi = fmaxf(mxi, __shfl_xor(mxi, 2));
        mxi = fmaxf(mxi, __shfl_xor(mxi, 4));
        mxi = fmaxf(mxi, __shfl_xor(mxi, 8));
        float smi = 0.0f;
#pragma unroll
        for (int kb = 0; kb < 14; ++kb) {
            float e = expf(S[kb][i] - mxi);
            S[kb][i] = e;
            smi += e;
        }
        smi += __shfl_xor(smi, 1);
        smi += __shfl_xor(smi, 2);
        smi += __shfl_xor(smi, 4);
        smi += __shfl_xor(smi, 8);
        float rinv = 1.0f / smi;
#pragma unroll
        for (int kb = 0; kb < 14; ++kb)
            Pbuf[wave][m][kb * 16 + c] = f2bf(S[kb][i] * rinv);
    }

    // ---- PV: P A-frags from wave-private LDS, V from prefetched regs
    f32x4 O[2] = {};
#pragma unroll
    for (int ks = 0; ks < 7; ++ks) {
        bf16x8 pf = *(const bf16x8*)&Pbuf[wave][c][ks * 32 + lg * 8];
#pragma unroll
        for (int nb = 0; nb < 2; ++nb)
            O[nb] = __builtin_amdgcn_mfma_f32_16x16x32_bf16(pf, vf[ks][nb], O[nb], 0, 0, 0);
    }
    // ---- write out (C layout)
#pragma unroll
    for (int i = 0; i < 4; ++i) {
        int m = lg * 4 + i;
        int gi = ti0 + wave * 2 + (m >> 3);
        int gj = tj0 + (m & 7);
        size_t t = ((size_t)(bb + gi * 64 + gj)) * 128 + h * 32;
        out[t + c]      = f2bf(O[0][i]);
        out[t + 16 + c] = f2bf(O[1][i]);
    }
}

extern "C" void kernel_launch(void* const* d_in, const int* in_sizes, int n_in,
                              void* d_out, int out_size, void* d_ws, size_t ws_size,
                              hipStream_t stream) {
    const float* query     = (const float*)d_in[0];
    const float* key_value = (const float*)d_in[1];
    const float* g1 = (const float*)d_in[2];
    const float* b1 = (const float*)d_in[3];
    const float* g2 = (const float*)d_in[4];
    const float* b2 = (const float*)d_in[5];
    const float* g3 = (const float*)d_in[6];
    const float* b3 = (const float*)d_in[7];
    const float* Wq  = (const float*)d_in[8];
    const float* bq  = (const float*)d_in[9];
    const float* Wkv = (const float*)d_in[10];
    const float* bkv = (const float*)d_in[11];
    const float* Wp  = (const float*)d_in[12];
    const float* bp  = (const float*)d_in[13];
    const float* rpb = (const float*)d_in[14];
    const float* W1  = (const float*)d_in[15];
    const float* bm1 = (const float*)d_in[16];
    const float* W2  = (const float*)d_in[17];
    const float* bm2 = (const float*)d_in[18];

    char* ws = (char*)d_ws;
    float*          xb   = (float*)(ws + 0);                  //  8 MB f32 [TOK][128]
    unsigned short* bufD = (unsigned short*)(ws + 8388608);   //  4 MB bf16: qnh -> attnh
    unsigned short* kvnh = (unsigned short*)(ws + 12582912);  //  4 MB bf16: kvn -> xnh
    unsigned short* qbh  = (unsigned short*)(ws + 16777216);  //  4 MB bf16 [TOK][128]
    unsigned short* kbh  = (unsigned short*)(ws + 20971520);  //  4 MB bf16 [TOK][128]
    unsigned short* vtg  = (unsigned short*)(ws + 25165824);  //  4 MB bf16 [16*32][4096]
    unsigned short* h1h  = (unsigned short*)(ws + 29360128);  // 16 MB bf16 [TOK][512]
    unsigned short* Wt   = (unsigned short*)(ws + 46137344);  // 384 KB bf16
    unsigned short* WtQ  = Wt;
    unsigned short* WtKV = Wt + 16384;
    unsigned short* WtP  = Wt + 49152;
    unsigned short* WtW1 = Wt + 65536;
    unsigned short* WtW2 = Wt + 131072;

    const float qscale = 0.17677669529663687f;  // HD^-0.5

    prep_kernel<<<8384, 256, 0, stream>>>(query, key_value, g1, b1, g2, b2,
                                          Wq, Wkv, Wp, W1, W2, bufD, kvnh, Wt);
    gemm_mfma<0,128><<<dim3(256, 2), 256, 0, stream>>>(bufD, WtQ,  bq,  nullptr, nullptr, qbh, nullptr, 128, qscale);
    gemm_mfma<3,128><<<dim3(256, 4), 256, 0, stream>>>(kvnh, WtKV, bkv, nullptr, nullptr, kbh, vtg,     256, 1.0f);
    nat_attn<<<1024, 256, 0, stream>>>(qbh, kbh, vtg, rpb, bufD);
    gemm_p_ln<<<512, 256, 0, stream>>>(bufD, WtP, bp, key_value, g3, b3, xb, kvnh);
    gemm_mfma<2,128><<<dim3(256, 8), 256, 0, stream>>>(kvnh, WtW1, bm1, nullptr, nullptr, h1h, nullptr, 512, 1.0f);
    gemm_mfma<1,512><<<dim3(256, 2), 256, 0, stream>>>(h1h,  WtW2, bm2, xb, (float*)d_out, nullptr, nullptr, 128, 1.0f);
}

// Round 6
// 181.933 us; speedup vs baseline: 1.1580x; 1.1341x over previous
//
#include <hip/hip_runtime.h>
#include <math.h>

// B=4, H=W=64, C=128, NH=4, HD=32, K=7, TOK=16384
#define TOK 16384

typedef __attribute__((ext_vector_type(8))) __bf16 bf16x8;
typedef __attribute__((ext_vector_type(4))) __bf16 bf16x4;
typedef __attribute__((ext_vector_type(4))) float f32x4;

__device__ inline unsigned short f2bf(float f) {
    union { float f; unsigned int u; } v; v.f = f;
    unsigned int r = v.u + 0x7fffu + ((v.u >> 16) & 1u);
    return (unsigned short)(r >> 16);
}

// ---------------- LayerNorm body: one wave per token, 2 ch/lane, bf16 out ----
__device__ inline void ln_body(const float* __restrict__ x, const float* __restrict__ g,
                               const float* __restrict__ b, unsigned short* __restrict__ y,
                               int tok, int lane)
{
    float2 v = ((const float2*)(x + (size_t)tok * 128))[lane];
    float s = v.x + v.y;
#pragma unroll
    for (int m = 32; m >= 1; m >>= 1) s += __shfl_xor(s, m);
    float mean = s * (1.0f / 128.0f);
    float dx = v.x - mean, dy = v.y - mean;
    float vs = dx * dx + dy * dy;
#pragma unroll
    for (int m = 32; m >= 1; m >>= 1) vs += __shfl_xor(vs, m);
    float rs = rsqrtf(vs * (1.0f / 128.0f) + 1e-5f);
    float2 gg = ((const float2*)g)[lane];
    float2 bb = ((const float2*)b)[lane];
    float ox = dx * rs * gg.x + bb.x;
    float oy = dy * rs * gg.y + bb.y;
    unsigned int pk = (unsigned int)f2bf(ox) | ((unsigned int)f2bf(oy) << 16);
    ((unsigned int*)(y + (size_t)tok * 128))[lane] = pk;
}

// ---------------- prep: LN1 + LN2 + tiled weight transpose to bf16 ----------
__global__ __launch_bounds__(256) void prep_kernel(
    const float* __restrict__ query, const float* __restrict__ key_value,
    const float* __restrict__ g1, const float* __restrict__ b1,
    const float* __restrict__ g2, const float* __restrict__ b2,
    const float* __restrict__ Wq, const float* __restrict__ Wkv,
    const float* __restrict__ Wp, const float* __restrict__ W1, const float* __restrict__ W2,
    unsigned short* __restrict__ qnh, unsigned short* __restrict__ kvnh,
    unsigned short* __restrict__ Wt)
{
    int blk = blockIdx.x, tid = threadIdx.x;
    if (blk < 8192) {
        int lane = tid & 63;
        if (blk < 4096) ln_body(query,     g1, b1, qnh,  blk * 4 + (tid >> 6), lane);
        else            ln_body(key_value, g2, b2, kvnh, (blk - 4096) * 4 + (tid >> 6), lane);
        return;
    }
    __shared__ float tile[32][33];
    int t = blk - 8192;
    const float* src; unsigned short* dst; int Kd, Nd, li;
    if      (t < 16)  { src = Wq;  dst = Wt;          Kd = 128; Nd = 128; li = t; }
    else if (t < 48)  { src = Wkv; dst = Wt + 16384;  Kd = 128; Nd = 256; li = t - 16; }
    else if (t < 64)  { src = Wp;  dst = Wt + 49152;  Kd = 128; Nd = 128; li = t - 48; }
    else if (t < 128) { src = W1;  dst = Wt + 65536;  Kd = 128; Nd = 512; li = t - 64; }
    else              { src = W2;  dst = Wt + 131072; Kd = 512; Nd = 128; li = t - 128; }
    int ntc = Nd >> 5;
    int k0 = (li / ntc) * 32, n0 = (li % ntc) * 32;
    int r = tid >> 3, c4 = (tid & 7) * 4;
    float4 v = *(const float4*)(src + (size_t)(k0 + r) * Nd + n0 + c4);
    tile[r][c4 + 0] = v.x; tile[r][c4 + 1] = v.y;
    tile[r][c4 + 2] = v.z; tile[r][c4 + 3] = v.w;
    __syncthreads();
    ushort4 o;
    o.x = f2bf(tile[c4 + 0][r]);
    o.y = f2bf(tile[c4 + 1][r]);
    o.z = f2bf(tile[c4 + 2][r]);
    o.w = f2bf(tile[c4 + 3][r]);
    *(ushort4*)(dst + (size_t)(n0 + r) * Kd + k0 + c4) = o;
}

// ---------------- fused Q+KV projection: single-wave blocks, 32x64 tile -----
// grid (512, 6): y<2 -> Q cols y*64; y>=2 -> KV cols (y-2)*64. K=128.
__global__ __launch_bounds__(64) void gemm_qkv(
    const unsigned short* __restrict__ qnh, const unsigned short* __restrict__ kvnh,
    const unsigned short* __restrict__ Wt,  // WtQ at 0, WtKV at +16384
    const float* __restrict__ bq, const float* __restrict__ bkv,
    unsigned short* __restrict__ qbh, unsigned short* __restrict__ kbh,
    unsigned short* __restrict__ vbh, float qscale)
{
    const int lane = threadIdx.x;
    const int lr = lane & 15, lg = lane >> 4;
    const int y = blockIdx.y;
    const unsigned short* A;
    const unsigned short* Wb;
    const float* bias;
    int n0;
    if (y < 2) { A = qnh;  Wb = Wt;          bias = bq;  n0 = y * 64; }
    else       { A = kvnh; Wb = Wt + 16384;  bias = bkv; n0 = (y - 2) * 64; }
    const int m0 = blockIdx.x * 32;
    f32x4 acc[2][4] = {};
#pragma unroll
    for (int k0 = 0; k0 < 128; k0 += 32) {
        bf16x8 a[2], b[4];
#pragma unroll
        for (int mf = 0; mf < 2; ++mf)
            a[mf] = *(const bf16x8*)(A + (size_t)(m0 + mf * 16 + lr) * 128 + k0 + lg * 8);
#pragma unroll
        for (int nf = 0; nf < 4; ++nf)
            b[nf] = *(const bf16x8*)(Wb + (size_t)(n0 + nf * 16 + lr) * 128 + k0 + lg * 8);
#pragma unroll
        for (int mf = 0; mf < 2; ++mf)
#pragma unroll
            for (int nf = 0; nf < 4; ++nf)
                acc[mf][nf] = __builtin_amdgcn_mfma_f32_16x16x32_bf16(a[mf], b[nf], acc[mf][nf], 0, 0, 0);
    }
#pragma unroll
    for (int nf = 0; nf < 4; ++nf) {
        int gc = n0 + nf * 16 + lr;
        float bs = bias[gc];
#pragma unroll
        for (int mf = 0; mf < 2; ++mf) {
            int gr0 = m0 + mf * 16 + lg * 4;
#pragma unroll
            for (int r = 0; r < 4; ++r) {
                float v = acc[mf][nf][r] + bs;
                size_t tok = (size_t)(gr0 + r);
                if (y < 2)          qbh[tok * 128 + gc] = f2bf(v * qscale);
                else if (gc < 128)  kbh[tok * 128 + gc] = f2bf(v);
                else                vbh[tok * 128 + gc - 128] = f2bf(v);
            }
        }
    }
}

// ---------------- generic single-wave GEMM 32x64, templated K ---------------
// MODE 1: outF = v + res (f32)   MODE 2: outH = bf16(gelu_exact(v))
template<int MODE, int TK>
__global__ __launch_bounds__(64) void gemm_w(
    const unsigned short* __restrict__ A, const unsigned short* __restrict__ Wb,
    const float* __restrict__ bias, const float* __restrict__ res,
    float* __restrict__ outF, unsigned short* __restrict__ outH, int N)
{
    const int lane = threadIdx.x;
    const int lr = lane & 15, lg = lane >> 4;
    const int m0 = blockIdx.x * 32;
    const int n0 = blockIdx.y * 64;
    f32x4 acc[2][4] = {};
#pragma unroll 4
    for (int k0 = 0; k0 < TK; k0 += 32) {
        bf16x8 a[2], b[4];
#pragma unroll
        for (int mf = 0; mf < 2; ++mf)
            a[mf] = *(const bf16x8*)(A + (size_t)(m0 + mf * 16 + lr) * TK + k0 + lg * 8);
#pragma unroll
        for (int nf = 0; nf < 4; ++nf)
            b[nf] = *(const bf16x8*)(Wb + (size_t)(n0 + nf * 16 + lr) * TK + k0 + lg * 8);
#pragma unroll
        for (int mf = 0; mf < 2; ++mf)
#pragma unroll
            for (int nf = 0; nf < 4; ++nf)
                acc[mf][nf] = __builtin_amdgcn_mfma_f32_16x16x32_bf16(a[mf], b[nf], acc[mf][nf], 0, 0, 0);
    }
#pragma unroll
    for (int nf = 0; nf < 4; ++nf) {
        int gc = n0 + nf * 16 + lr;
        float bs = bias[gc];
#pragma unroll
        for (int mf = 0; mf < 2; ++mf) {
            int gr0 = m0 + mf * 16 + lg * 4;
#pragma unroll
            for (int r = 0; r < 4; ++r) {
                float v = acc[mf][nf][r] + bs;
                size_t idx = (size_t)(gr0 + r) * N + gc;
                if (MODE == 1) outF[idx] = v + res[idx];
                if (MODE == 2) {
                    float gl = 0.5f * v * (1.0f + erff(v * 0.70710678118654752f));
                    outH[idx] = f2bf(gl);
                }
            }
        }
    }
}

// ---------------- Wp GEMM + residual + fused LN3 (4-wave blocks) ------------
__global__ __launch_bounds__(256) void gemm_p_ln(
    const unsigned short* __restrict__ A, const unsigned short* __restrict__ Wt,
    const float* __restrict__ bias, const float* __restrict__ res,
    const float* __restrict__ g, const float* __restrict__ bln,
    float* __restrict__ xb, unsigned short* __restrict__ y)
{
    __shared__ float xs[32][132];
    const int wave = threadIdx.x >> 6, lane = threadIdx.x & 63;
    const int m0 = blockIdx.x * 32;
    const int n0 = wave * 32;
    const int lr = lane & 15, lg = lane >> 4;
    f32x4 acc[2][2] = {};
#pragma unroll
    for (int k0 = 0; k0 < 128; k0 += 32) {
        bf16x8 a[2], b[2];
#pragma unroll
        for (int mf = 0; mf < 2; ++mf)
            a[mf] = *(const bf16x8*)(A + (size_t)(m0 + mf * 16 + lr) * 128 + k0 + lg * 8);
#pragma unroll
        for (int nf = 0; nf < 2; ++nf)
            b[nf] = *(const bf16x8*)(Wt + (size_t)(n0 + nf * 16 + lr) * 128 + k0 + lg * 8);
#pragma unroll
        for (int mf = 0; mf < 2; ++mf)
#pragma unroll
            for (int nf = 0; nf < 2; ++nf)
                acc[mf][nf] = __builtin_amdgcn_mfma_f32_16x16x32_bf16(a[mf], b[nf], acc[mf][nf], 0, 0, 0);
    }
#pragma unroll
    for (int nf = 0; nf < 2; ++nf) {
        int gc = n0 + nf * 16 + lr;
        float bs = bias[gc];
#pragma unroll
        for (int mf = 0; mf < 2; ++mf) {
            int lr0 = mf * 16 + lg * 4;
#pragma unroll
            for (int r = 0; r < 4; ++r) {
                size_t idx = (size_t)(m0 + lr0 + r) * 128 + gc;
                float v = acc[mf][nf][r] + bs + res[idx];
                xb[idx] = v;
                xs[lr0 + r][gc] = v;
            }
        }
    }
    __syncthreads();
    const int r = threadIdx.x >> 3, t8 = threadIdx.x & 7;
    float vals[16];
#pragma unroll
    for (int j = 0; j < 16; ++j) vals[j] = xs[r][t8 * 16 + j];
    float s = 0.0f;
#pragma unroll
    for (int j = 0; j < 16; ++j) s += vals[j];
    s += __shfl_xor(s, 1); s += __shfl_xor(s, 2); s += __shfl_xor(s, 4);
    float mean = s * (1.0f / 128.0f);
    float vv = 0.0f;
#pragma unroll
    for (int j = 0; j < 16; ++j) { float d = vals[j] - mean; vv += d * d; }
    vv += __shfl_xor(vv, 1); vv += __shfl_xor(vv, 2); vv += __shfl_xor(vv, 4);
    float rs = rsqrtf(vv * (1.0f / 128.0f) + 1e-5f);
#pragma unroll
    for (int jj = 0; jj < 4; ++jj) {
        float4 gg = ((const float4*)g)[t8 * 4 + jj];
        float4 bb = ((const float4*)bln)[t8 * 4 + jj];
        ushort4 o;
        o.x = f2bf((vals[jj * 4 + 0] - mean) * rs * gg.x + bb.x);
        o.y = f2bf((vals[jj * 4 + 1] - mean) * rs * gg.y + bb.y);
        o.z = f2bf((vals[jj * 4 + 2] - mean) * rs * gg.z + bb.z);
        o.w = f2bf((vals[jj * 4 + 3] - mean) * rs * gg.w + bb.w);
        *(ushort4*)(y + (size_t)(m0 + r) * 128 + t8 * 16 + jj * 4) = o;
    }
}

// ---------------- Neighborhood attention v3: LDS-staged MFMA ----------------
// Block = (b, head, 8x8 query tile), 4 waves; wave w: 16 queries (rows 2w,2w+1).
// LDS: Ks 224x40 bf16 (unioned with P 4x16x232), Vs transposed 32x232, rpb.
__global__ __launch_bounds__(256) void nat_attn(
    const unsigned short* __restrict__ qbh,   // [TOK][128] bf16 (pre-scaled)
    const unsigned short* __restrict__ kbh,   // [TOK][128] bf16
    const unsigned short* __restrict__ vbh,   // [TOK][128] bf16
    const float* __restrict__ rpb,            // [4][13][13]
    unsigned short* __restrict__ out)         // [TOK][128] bf16
{
    __shared__ unsigned short KP[14848];      // Ks[224][40] then P[4][16][232]
    __shared__ unsigned short Vsm[32 * 232];  // Vs[d][pos], pos < 224
    __shared__ float rpbs[169];
    const int tid = threadIdx.x;
    const int wave = tid >> 6, lane = tid & 63;
    const int c = lane & 15, lg = lane >> 4;
    const int bid = blockIdx.x;
    const int tile = bid & 63, h = (bid >> 6) & 3, b = bid >> 8;
    const int ti0 = (tile >> 3) * 8, tj0 = (tile & 7) * 8;
    const int hr0 = min(max(ti0 - 3, 0), 50);
    const int hc0 = min(max(tj0 - 3, 0), 50);
    const int bb = b << 12;

    if (tid < 169) rpbs[tid] = rpb[h * 169 + tid];

    // ---- stage K into Ks[pos][ch] (stride 40) and V transposed Vs[ch][pos]
    for (int u = tid; u < 896; u += 256) {
        int tok = u >> 2, chunk = u & 3;
        int tr = tok >> 4, tc = tok & 15;
        size_t src = (size_t)(bb + (hr0 + tr) * 64 + hc0 + tc) * 128 + h * 32 + chunk * 8;
        int4 kw = *(const int4*)(kbh + src);
        *(int4*)&KP[tok * 40 + chunk * 8] = kw;
        int4 vw = *(const int4*)(vbh + src);
        const unsigned short* v8 = (const unsigned short*)&vw;
#pragma unroll
        for (int k = 0; k < 8; ++k)
            Vsm[(chunk * 8 + k) * 232 + tok] = v8[k];
    }

    // ---- Q A-frag (m = c)
    const int gi_m = ti0 + wave * 2 + (c >> 3);
    const int gj_m = tj0 + (c & 7);
    const int tq = bb + gi_m * 64 + gj_m;
    bf16x8 qf = *(const bf16x8*)(qbh + (size_t)tq * 128 + h * 32 + lg * 8);
    __syncthreads();

    // ---- QK^T: 14 MFMAs, K frags from LDS (conflict-free b128)
    f32x4 S[14];
#pragma unroll
    for (int kb = 0; kb < 14; ++kb) {
        bf16x8 kf = *(const bf16x8*)&KP[(kb * 16 + c) * 40 + lg * 8];
        f32x4 z = {0.0f, 0.0f, 0.0f, 0.0f};
        S[kb] = __builtin_amdgcn_mfma_f32_16x16x32_bf16(qf, kf, z, 0, 0, 0);
    }
    __syncthreads();   // all waves done reading Ks; region becomes P

    // ---- bias + mask + softmax (C layout: row=lg*4+i, col=c), write P bf16
#pragma unroll
    for (int i = 0; i < 4; ++i) {
        int m = lg * 4 + i;
        int gi = ti0 + wave * 2 + (m >> 3);
        int gj = tj0 + (m & 7);
        int si = min(max(gi - 3, 0), 57), sj = min(max(gj - 3, 0), 57);
        bool cv = (unsigned)(hc0 + c - sj) < 7u;
        int rjc = min(max(hc0 + c - gj + 6, 0), 12);
        float mxi = -INFINITY;
#pragma unroll
        for (int kb = 0; kb < 14; ++kb) {
            bool rv = (unsigned)(hr0 + kb - si) < 7u;
            int ric = min(max(hr0 + kb - gi + 6, 0), 12);
            float bias = rpbs[rjc + ric * 13];
            float s = (rv && cv) ? S[kb][i] + bias : -1e30f;
            S[kb][i] = s;
            mxi = fmaxf(mxi, s);
        }
        mxi = fmaxf(mxi, __shfl_xor(mxi, 1));
        mxi = fmaxf(mxi, __shfl_xor(mxi, 2));
        mxi = fmaxf(mxi, __shfl_xor(mxi, 4));
        mxi = fmaxf(mxi, __shfl_xor(mxi, 8));
        float smi = 0.0f;
#pragma unroll
        for (int kb = 0; kb < 14; ++kb) {
            float e = expf(S[kb][i] - mxi);
            S[kb][i] = e;
            smi += e;
        }
        smi += __shfl_xor(smi, 1);
        smi += __shfl_xor(smi, 2);
        smi += __shfl_xor(smi, 4);
        smi += __shfl_xor(smi, 8);
        float rinv = 1.0f / smi;
#pragma unroll
        for (int kb = 0; kb < 14; ++kb)
            KP[(wave * 16 + m) * 232 + kb * 16 + c] = f2bf(S[kb][i] * rinv);
    }

    // ---- PV: P A-frags (wave-private, b64 pairs) x Vs B-frags (b64 pairs)
    f32x4 O[2] = {};
#pragma unroll
    for (int ks = 0; ks < 7; ++ks) {
        int po = (wave * 16 + c) * 232 + ks * 32 + lg * 8;
        bf16x4 plo = *(const bf16x4*)&KP[po];
        bf16x4 phi = *(const bf16x4*)&KP[po + 4];
        bf16x8 pf = __builtin_shufflevector(plo, phi, 0, 1, 2, 3, 4, 5, 6, 7);
#pragma unroll
        for (int nb = 0; nb < 2; ++nb) {
            int vo = (nb * 16 + c) * 232 + ks * 32 + lg * 8;
            bf16x4 vlo = *(const bf16x4*)&Vsm[vo];
            bf16x4 vhi = *(const bf16x4*)&Vsm[vo + 4];
            bf16x8 vf = __builtin_shufflevector(vlo, vhi, 0, 1, 2, 3, 4, 5, 6, 7);
            O[nb] = __builtin_amdgcn_mfma_f32_16x16x32_bf16(pf, vf, O[nb], 0, 0, 0);
        }
    }
    // ---- write out (C layout)
#pragma unroll
    for (int i = 0; i < 4; ++i) {
        int m = lg * 4 + i;
        int gi = ti0 + wave * 2 + (m >> 3);
        int gj = tj0 + (m & 7);
        size_t t = ((size_t)(bb + gi * 64 + gj)) * 128 + h * 32;
        out[t + c]      = f2bf(O[0][i]);
        out[t + 16 + c] = f2bf(O[1][i]);
    }
}

extern "C" void kernel_launch(void* const* d_in, const int* in_sizes, int n_in,
                              void* d_out, int out_size, void* d_ws, size_t ws_size,
                              hipStream_t stream) {
    const float* query     = (const float*)d_in[0];
    const float* key_value = (const float*)d_in[1];
    const float* g1 = (const float*)d_in[2];
    const float* b1 = (const float*)d_in[3];
    const float* g2 = (const float*)d_in[4];
    const float* b2 = (const float*)d_in[5];
    const float* g3 = (const float*)d_in[6];
    const float* b3 = (const float*)d_in[7];
    const float* Wq  = (const float*)d_in[8];
    const float* bq  = (const float*)d_in[9];
    const float* Wkv = (const float*)d_in[10];
    const float* bkv = (const float*)d_in[11];
    const float* Wp  = (const float*)d_in[12];
    const float* bp  = (const float*)d_in[13];
    const float* rpb = (const float*)d_in[14];
    const float* W1  = (const float*)d_in[15];
    const float* bm1 = (const float*)d_in[16];
    const float* W2  = (const float*)d_in[17];
    const float* bm2 = (const float*)d_in[18];

    char* ws = (char*)d_ws;
    float*          xb   = (float*)(ws + 0);                  //  8 MB f32 [TOK][128]
    unsigned short* bufD = (unsigned short*)(ws + 8388608);   //  4 MB bf16: qnh -> attn
    unsigned short* kvnh = (unsigned short*)(ws + 12582912);  //  4 MB bf16: kvn -> xnh
    unsigned short* qbh  = (unsigned short*)(ws + 16777216);  //  4 MB bf16 [TOK][128]
    unsigned short* kbh  = (unsigned short*)(ws + 20971520);  //  4 MB bf16 [TOK][128]
    unsigned short* vbh  = (unsigned short*)(ws + 25165824);  //  4 MB bf16 [TOK][128]
    unsigned short* h1h  = (unsigned short*)(ws + 29360128);  // 16 MB bf16 [TOK][512]
    unsigned short* Wt   = (unsigned short*)(ws + 46137344);  // 384 KB bf16
    unsigned short* WtP  = Wt + 49152;
    unsigned short* WtW1 = Wt + 65536;
    unsigned short* WtW2 = Wt + 131072;

    const float qscale = 0.17677669529663687f;  // HD^-0.5

    prep_kernel<<<8384, 256, 0, stream>>>(query, key_value, g1, b1, g2, b2,
                                          Wq, Wkv, Wp, W1, W2, bufD, kvnh, Wt);
    gemm_qkv<<<dim3(512, 6), 64, 0, stream>>>(bufD, kvnh, Wt, bq, bkv, qbh, kbh, vbh, qscale);
    nat_attn<<<1024, 256, 0, stream>>>(qbh, kbh, vbh, rpb, bufD);
    gemm_p_ln<<<512, 256, 0, stream>>>(bufD, WtP, bp, key_value, g3, b3, xb, kvnh);
    gemm_w<2, 128><<<dim3(512, 8), 64, 0, stream>>>(kvnh, WtW1, bm1, nullptr, nullptr, h1h, 512);
    gemm_w<1, 512><<<dim3(512, 2), 64, 0, stream>>>(h1h,  WtW2, bm2, xb, (float*)d_out, nullptr, 128);
}